// Round 1
// 236.600 us; speedup vs baseline: 1.0405x; 1.0405x over previous
//
#include <hip/hip_runtime.h>
#include <math.h>

#define DD 2048
#define EE 64
#define TM 32               // tokens per block (grid = 512 = 2 blocks/CU)
#define BK 64
#define NCHUNK (DD / BK)
#define THREADS 256
#define LDSX 34             // xs row stride (floats): [BK][LDSX], k-major
#define LDSW 68             // ws row stride (floats): [BK][LDSW], k-major

__global__ __launch_bounds__(THREADS) void router_kernel(
    const float* __restrict__ x, const float* __restrict__ W,
    const float* __restrict__ bias_g, float* __restrict__ out, int n_tokens)
{
    __shared__ __attribute__((aligned(16))) float xs[BK * LDSX];
    __shared__ __attribute__((aligned(16))) float ws[BK * LDSW];
    __shared__ __attribute__((aligned(16))) float logits[TM * (EE + 1)];

    const int tid = threadIdx.x;
    const int tx  = tid & 15;        // expert group: experts tx*4 .. tx*4+3
    const int ty  = tid >> 4;        // token group:  tokens  ty*2 .. ty*2+1
    const int tBase = blockIdx.x * TM;

    // loader mappings (bank-conflict-free transposed stores, see comments)
    const int xt = tid >> 3;         // x loader: token row 0..31
    const int xc = tid & 7;          // x loader: f4 col 0..7  (k4 = xc + 8p)
    const int we = tid >> 2;         // W loader: expert row 0..63
    const int wc = tid & 3;          // W loader: f4 col 0..3  (k4 = wc + 4p)

    const float* xrow = x + (size_t)(tBase + xt) * DD;
    const float* wrow = W + (size_t)we * DD;

    float acc[2][4];
#pragma unroll
    for (int t = 0; t < 2; ++t)
#pragma unroll
        for (int j = 0; j < 4; ++j) acc[t][j] = 0.f;

    const float4 bv4 = *(const float4*)&bias_g[tx * 4];

    float4 rx[2], rw[4];

    // global loads: 8 consecutive xc-lanes cover 128B of one x row (coalesced);
    // 4 consecutive wc-lanes cover 64B of one W row; p-loop consumes the rest
    // of each 128B line out of L1 (W chunk 16KB fits L1).
#define LOAD_TILES(k0)                                                       \
    {                                                                        \
        _Pragma("unroll")                                                    \
        for (int p = 0; p < 2; ++p)                                          \
            rx[p] = *(const float4*)&xrow[(k0) + 4 * (xc + 8 * p)];          \
        _Pragma("unroll")                                                    \
        for (int p = 0; p < 4; ++p)                                          \
            rw[p] = *(const float4*)&wrow[(k0) + 4 * (wc + 4 * p)];          \
    }

    LOAD_TILES(0);

    for (int c = 0; c < NCHUNK; ++c) {
        __syncthreads();  // previous compute phase done; safe to overwrite LDS

        // x transposed store: bank = (8*xc + xt + 2j) mod 32 -> 2-way (free)
#pragma unroll
        for (int p = 0; p < 2; ++p) {
            const int k = 4 * (xc + 8 * p);
            xs[(k + 0) * LDSX + xt] = rx[p].x;
            xs[(k + 1) * LDSX + xt] = rx[p].y;
            xs[(k + 2) * LDSX + xt] = rx[p].z;
            xs[(k + 3) * LDSX + xt] = rx[p].w;
        }
        // W transposed store: bank = (16*(wc&1) + 4j + we) mod 32 -> 2-way (free)
#pragma unroll
        for (int p = 0; p < 4; ++p) {
            const int k = 4 * (wc + 4 * p);
            ws[(k + 0) * LDSW + we] = rw[p].x;
            ws[(k + 1) * LDSW + we] = rw[p].y;
            ws[(k + 2) * LDSW + we] = rw[p].z;
            ws[(k + 3) * LDSW + we] = rw[p].w;
        }
        __syncthreads();

        if (c + 1 < NCHUNK) {
            const int k0n = (c + 1) * BK;
            LOAD_TILES(k0n);
        }

        // inner product: 2 LDS reads (b64 + b128, both <=2-way) per 8 FMAs
#pragma unroll
        for (int k = 0; k < BK; ++k) {
            const float2 xv = *(const float2*)&xs[k * LDSX + ty * 2];
            const float4 wv = *(const float4*)&ws[k * LDSW + tx * 4];
            acc[0][0] += xv.x * wv.x; acc[0][1] += xv.x * wv.y;
            acc[0][2] += xv.x * wv.z; acc[0][3] += xv.x * wv.w;
            acc[1][0] += xv.y * wv.x; acc[1][1] += xv.y * wv.y;
            acc[1][2] += xv.y * wv.z; acc[1][3] += xv.y * wv.w;
        }
    }

    // -------- epilogue: logits -> LDS, per-token top-2 + softmax --------
    __syncthreads();
#pragma unroll
    for (int t = 0; t < 2; ++t) {
        const int row = (ty * 2 + t) * (EE + 1);
        logits[row + tx * 4 + 0] = acc[t][0] + bv4.x;
        logits[row + tx * 4 + 1] = acc[t][1] + bv4.y;
        logits[row + tx * 4 + 2] = acc[t][2] + bv4.z;
        logits[row + tx * 4 + 3] = acc[t][3] + bv4.w;
    }
    __syncthreads();

    if (tid < TM) {
        const float* lrow = &logits[tid * (EE + 1)];
        float v1 = -INFINITY, v2 = -INFINITY;
        int   i1 = 0, i2 = 0;
        for (int e = 0; e < EE; ++e) {
            const float v = lrow[e];
            if (v > v1) { v2 = v1; i2 = i1; v1 = v; i1 = e; }
            else if (v > v2) { v2 = v; i2 = e; }
        }
        // softmax over [v1, v2] (v1 >= v2): g1 = 1/(1+e^{v2-v1})
        const float ed = expf(v2 - v1);
        const float inv = 1.f / (1.f + ed);
        const int tok = tBase + tid;
        out[tok * 2 + 0] = inv;
        out[tok * 2 + 1] = ed * inv;
        float* oidx = out + (size_t)2 * n_tokens;
        oidx[tok * 2 + 0] = (float)i1;
        oidx[tok * 2 + 1] = (float)i2;
    }
}

extern "C" void kernel_launch(void* const* d_in, const int* in_sizes, int n_in,
                              void* d_out, int out_size, void* d_ws, size_t ws_size,
                              hipStream_t stream) {
    const float* x = (const float*)d_in[0];
    const float* W = (const float*)d_in[1];
    const float* b = (const float*)d_in[2];
    float* out = (float*)d_out;

    const int n_tokens = in_sizes[0] / DD;      // 16384
    const int n_blocks = n_tokens / TM;         // 512 -> 2 blocks/CU

    router_kernel<<<n_blocks, THREADS, 0, stream>>>(x, W, b, out, n_tokens);
}

// Round 2
// 234.259 us; speedup vs baseline: 1.0508x; 1.0100x over previous
//
#include <hip/hip_runtime.h>
#include <math.h>

#define DD 2048
#define EE 64
#define TM 32               // tokens per block (grid = 512 = 2 blocks/CU)
#define BK 64
#define NCHUNK (DD / BK)
#define THREADS 256
#define LDSX 34             // xs row stride (floats): [BK][LDSX], k-major
#define LDSW 68             // ws row stride (floats): [BK][LDSW], k-major

__global__ __launch_bounds__(THREADS) void router_kernel(
    const float* __restrict__ x, const float* __restrict__ W,
    const float* __restrict__ bias_g, float* __restrict__ out, int n_tokens)
{
    __shared__ __attribute__((aligned(16))) float xs[BK * LDSX];
    __shared__ __attribute__((aligned(16))) float ws[BK * LDSW];
    __shared__ __attribute__((aligned(16))) float logits[TM * (EE + 1)];

    const int tid = threadIdx.x;
    const int tx  = tid & 15;        // expert group: experts tx*4 .. tx*4+3
    const int ty  = tid >> 4;        // token group:  tokens  ty*2 .. ty*2+1
    const int tBase = blockIdx.x * TM;

    // loader mappings (bank-conflict-free transposed stores, see comments)
    const int xt = tid >> 3;         // x loader: token row 0..31
    const int xc = tid & 7;          // x loader: f4 col 0..7  (k4 = xc + 8p)
    const int we = tid >> 2;         // W loader: expert row 0..63
    const int wc = tid & 3;          // W loader: f4 col 0..3  (k4 = wc + 4p)

    const float* xrow = x + (size_t)(tBase + xt) * DD;
    const float* wrow = W + (size_t)we * DD;

    float acc[2][4];
#pragma unroll
    for (int t = 0; t < 2; ++t)
#pragma unroll
        for (int j = 0; j < 4; ++j) acc[t][j] = 0.f;

    const float4 bv4 = *(const float4*)&bias_g[tx * 4];

    float4 rx[2], rw[4];

    // global loads: 8 consecutive xc-lanes cover 128B of one x row (coalesced);
    // 4 consecutive wc-lanes cover 64B of one W row; p-loop consumes the rest
    // of each 128B line out of L1 (W chunk 16KB fits L1).
#define LOAD_TILES(k0)                                                       \
    {                                                                        \
        _Pragma("unroll")                                                    \
        for (int p = 0; p < 2; ++p)                                          \
            rx[p] = *(const float4*)&xrow[(k0) + 4 * (xc + 8 * p)];          \
        _Pragma("unroll")                                                    \
        for (int p = 0; p < 4; ++p)                                          \
            rw[p] = *(const float4*)&wrow[(k0) + 4 * (wc + 4 * p)];          \
    }

    LOAD_TILES(0);

    for (int c = 0; c < NCHUNK; ++c) {
        __syncthreads();  // previous compute phase done; safe to overwrite LDS

        // x transposed store: bank = (8*xc + xt + 2j) mod 32 -> 2-way (free)
#pragma unroll
        for (int p = 0; p < 2; ++p) {
            const int k = 4 * (xc + 8 * p);
            xs[(k + 0) * LDSX + xt] = rx[p].x;
            xs[(k + 1) * LDSX + xt] = rx[p].y;
            xs[(k + 2) * LDSX + xt] = rx[p].z;
            xs[(k + 3) * LDSX + xt] = rx[p].w;
        }
        // W transposed store: bank = (16*(wc&1) + 4j + we) mod 32 -> 2-way (free)
#pragma unroll
        for (int p = 0; p < 4; ++p) {
            const int k = 4 * (wc + 4 * p);
            ws[(k + 0) * LDSW + we] = rw[p].x;
            ws[(k + 1) * LDSW + we] = rw[p].y;
            ws[(k + 2) * LDSW + we] = rw[p].z;
            ws[(k + 3) * LDSW + we] = rw[p].w;
        }
        __syncthreads();

        if (c + 1 < NCHUNK) {
            const int k0n = (c + 1) * BK;
            LOAD_TILES(k0n);
        }

        // inner product: 2 LDS reads (b64 + b128, both <=2-way) per 8 FMAs
#pragma unroll
        for (int k = 0; k < BK; ++k) {
            const float2 xv = *(const float2*)&xs[k * LDSX + ty * 2];
            const float4 wv = *(const float4*)&ws[k * LDSW + tx * 4];
            acc[0][0] += xv.x * wv.x; acc[0][1] += xv.x * wv.y;
            acc[0][2] += xv.x * wv.z; acc[0][3] += xv.x * wv.w;
            acc[1][0] += xv.y * wv.x; acc[1][1] += xv.y * wv.y;
            acc[1][2] += xv.y * wv.z; acc[1][3] += xv.y * wv.w;
        }
    }

    // -------- epilogue: logits -> LDS, per-token top-2 + softmax --------
    __syncthreads();
#pragma unroll
    for (int t = 0; t < 2; ++t) {
        const int row = (ty * 2 + t) * (EE + 1);
        logits[row + tx * 4 + 0] = acc[t][0] + bv4.x;
        logits[row + tx * 4 + 1] = acc[t][1] + bv4.y;
        logits[row + tx * 4 + 2] = acc[t][2] + bv4.z;
        logits[row + tx * 4 + 3] = acc[t][3] + bv4.w;
    }
    __syncthreads();

    if (tid < TM) {
        const float* lrow = &logits[tid * (EE + 1)];
        float v1 = -INFINITY, v2 = -INFINITY;
        int   i1 = 0, i2 = 0;
        for (int e = 0; e < EE; ++e) {
            const float v = lrow[e];
            if (v > v1) { v2 = v1; i2 = i1; v1 = v; i1 = e; }
            else if (v > v2) { v2 = v; i2 = e; }
        }
        // softmax over [v1, v2] (v1 >= v2): g1 = 1/(1+e^{v2-v1})
        const float ed = expf(v2 - v1);
        const float inv = 1.f / (1.f + ed);
        const int tok = tBase + tid;
        out[tok * 2 + 0] = inv;
        out[tok * 2 + 1] = ed * inv;
        float* oidx = out + (size_t)2 * n_tokens;
        oidx[tok * 2 + 0] = (float)i1;
        oidx[tok * 2 + 1] = (float)i2;
    }
}

extern "C" void kernel_launch(void* const* d_in, const int* in_sizes, int n_in,
                              void* d_out, int out_size, void* d_ws, size_t ws_size,
                              hipStream_t stream) {
    const float* x = (const float*)d_in[0];
    const float* W = (const float*)d_in[1];
    const float* b = (const float*)d_in[2];
    float* out = (float*)d_out;

    const int n_tokens = in_sizes[0] / DD;      // 16384
    const int n_blocks = n_tokens / TM;         // 512 -> 2 blocks/CU

    router_kernel<<<n_blocks, THREADS, 0, stream>>>(x, W, b, out, n_tokens);
}

// Round 4
// 203.196 us; speedup vs baseline: 1.2115x; 1.1529x over previous
//
#include <hip/hip_runtime.h>
#include <math.h>

#define DD 2048
#define EE 64
#define TM 32                 // tokens per block; grid = 512 = 2 blocks/CU
#define BK 64                 // K per chunk (2 MFMA K-steps)
#define NCHUNK (DD / BK)      // 32
#define THREADS 256

#define ROWB 144              // LDS row stride in bytes (72 f16): 16B-aligned,
                              // 144/4=36 banks -> bank = (4*row + k/4)%32:
                              // fragment reads spread 2-way (free)
#define XPLANE (TM * ROWB)            // 4608 B
#define WPLANE (EE * ROWB)            // 9216 B
#define BUFB   (2 * XPLANE + 2 * WPLANE)  // 27648 B per buffer (xh,xl,wh,wl)

typedef _Float16 f16x8 __attribute__((ext_vector_type(8)));
typedef _Float16 f16x4 __attribute__((ext_vector_type(4)));
typedef float    f32x4 __attribute__((ext_vector_type(4)));

// split v*32 into f16 hi + f16 lo (2-way split, residual ~2^-21 relative)
__device__ static inline void split_f4(const float4 v, f16x4& hi, f16x4& lo) {
    const float S = 32.f;     // keeps lo parts out of f16 subnormal flush range
    const float a0 = v.x * S, a1 = v.y * S, a2 = v.z * S, a3 = v.w * S;
    const _Float16 h0 = (_Float16)a0, h1 = (_Float16)a1;
    const _Float16 h2 = (_Float16)a2, h3 = (_Float16)a3;
    hi = (f16x4){h0, h1, h2, h3};
    lo = (f16x4){(_Float16)(a0 - (float)h0), (_Float16)(a1 - (float)h1),
                 (_Float16)(a2 - (float)h2), (_Float16)(a3 - (float)h3)};
}

__global__ __launch_bounds__(THREADS) void router_kernel(
    const float* __restrict__ x, const float* __restrict__ W,
    const float* __restrict__ bias_g, float* __restrict__ out, int n_tokens)
{
    __shared__ __attribute__((aligned(16))) char  lds[2 * BUFB];       // 55296 B
    __shared__ __attribute__((aligned(16))) float logits[TM * (EE + 1)]; // 8320 B

    const int tid   = threadIdx.x;
    const int tBase = blockIdx.x * TM;

    // ---- staging lane mappings ----
    const int xt = tid >> 3;          // x loader: token row 0..31
    const int xc = tid & 7;           // x loader: f4 col (k4 = xc + 8p)
    const int we = tid >> 2;          // W loader: expert row 0..63
    const int wc = tid & 3;           // W loader: f4 col (k4 = wc + 4q)

    const float* xrow = x + (size_t)(tBase + xt) * DD + xc * 4;
    const float* wrow = W + (size_t)we * DD + wc * 4;

    float4 rx[2], rw[4];

#define LOADX(c) { _Pragma("unroll") for (int p = 0; p < 2; ++p) \
        rx[p] = *(const float4*)&xrow[(c) * BK + p * 32]; }
#define LOADW(c) { _Pragma("unroll") for (int q = 0; q < 4; ++q) \
        rw[q] = *(const float4*)&wrow[(c) * BK + q * 16]; }

#define WRITE_STAGE(buf) { \
    char* base = lds + (buf) * BUFB; \
    char* xh = base; char* xl = base + XPLANE; \
    char* wh = base + 2 * XPLANE; char* wl = base + 2 * XPLANE + WPLANE; \
    _Pragma("unroll") for (int p = 0; p < 2; ++p) { \
        f16x4 hi, lo; split_f4(rx[p], hi, lo); \
        const int off = xt * ROWB + (xc + 8 * p) * 8; \
        *(f16x4*)(xh + off) = hi; *(f16x4*)(xl + off) = lo; \
    } \
    _Pragma("unroll") for (int q = 0; q < 4; ++q) { \
        f16x4 hi, lo; split_f4(rw[q], hi, lo); \
        const int off = we * ROWB + (wc + 4 * q) * 8; \
        *(f16x4*)(wh + off) = hi; *(f16x4*)(wl + off) = lo; \
    } }

    // ---- MFMA fragment mappings (16x16x32 f16) ----
    // A: lane holds A[row = l&15][k = (l>>4)*8 + j]  (8 consecutive k, b128)
    // B: lane holds B[k = (l>>4)*8 + j][col = l&15] = W[col][k-run]
    // C/D: col = l&15, row = (l>>4)*4 + reg          (m89-verified)
    const int wv   = tid >> 6;        // wave 0..3
    const int lane = tid & 63;
    const int mtile = wv & 1;         // token tile (16 tokens)
    const int ngrp  = wv >> 1;        // expert half (2 N-tiles of 16)
    const int r16  = lane & 15;
    const int kg   = lane >> 4;

    const int aoff  = (mtile * 16 + r16) * ROWB + kg * 16;
    const int boff0 = ((ngrp * 2 + 0) * 16 + r16) * ROWB + kg * 16;
    const int boff1 = ((ngrp * 2 + 1) * 16 + r16) * ROWB + kg * 16;

    f32x4 acc0 = {0.f, 0.f, 0.f, 0.f};
    f32x4 acc1 = {0.f, 0.f, 0.f, 0.f};

#define COMPUTE(buf) { \
    char* base = lds + (buf) * BUFB; \
    char* xh = base; char* xl = base + XPLANE; \
    char* wh = base + 2 * XPLANE; char* wl = base + 2 * XPLANE + WPLANE; \
    _Pragma("unroll") for (int ks = 0; ks < 2; ++ks) { \
        const int ko = ks * 64; \
        const f16x8 ah  = *(const f16x8*)(xh + aoff  + ko); \
        const f16x8 al  = *(const f16x8*)(xl + aoff  + ko); \
        const f16x8 bh0 = *(const f16x8*)(wh + boff0 + ko); \
        const f16x8 bl0 = *(const f16x8*)(wl + boff0 + ko); \
        const f16x8 bh1 = *(const f16x8*)(wh + boff1 + ko); \
        const f16x8 bl1 = *(const f16x8*)(wl + boff1 + ko); \
        acc0 = __builtin_amdgcn_mfma_f32_16x16x32_f16(ah, bh0, acc0, 0, 0, 0); \
        acc0 = __builtin_amdgcn_mfma_f32_16x16x32_f16(al, bh0, acc0, 0, 0, 0); \
        acc0 = __builtin_amdgcn_mfma_f32_16x16x32_f16(ah, bl0, acc0, 0, 0, 0); \
        acc0 = __builtin_amdgcn_mfma_f32_16x16x32_f16(al, bl0, acc0, 0, 0, 0); \
        acc1 = __builtin_amdgcn_mfma_f32_16x16x32_f16(ah, bh1, acc1, 0, 0, 0); \
        acc1 = __builtin_amdgcn_mfma_f32_16x16x32_f16(al, bh1, acc1, 0, 0, 0); \
        acc1 = __builtin_amdgcn_mfma_f32_16x16x32_f16(ah, bl1, acc1, 0, 0, 0); \
        acc1 = __builtin_amdgcn_mfma_f32_16x16x32_f16(al, bl1, acc1, 0, 0, 0); \
    } }

    // ---- pipeline: 1 barrier/chunk, loads prefetched one chunk ahead ----
    LOADX(0); LOADW(0);
    WRITE_STAGE(0);
    LOADX(1); LOADW(1);

    int cur = 0;
    for (int c = 0; c < NCHUNK; ++c) {
        __syncthreads();              // buf[cur] visible; buf[cur^1] free
        COMPUTE(cur);
        if (c + 1 < NCHUNK) {
            WRITE_STAGE(cur ^ 1);     // chunk c+1 (waits vmcnt implicitly)
            if (c + 2 < NCHUNK) { LOADX(c + 2); LOADW(c + 2); }
        }
        cur ^= 1;
    }

    // ---- epilogue: unscale (acc = 1024 * logit), add bias, top-2 ----
    const int col0 = ngrp * 32 + r16;
    const int col1 = ngrp * 32 + 16 + r16;
    const float b0 = bias_g[col0];
    const float b1 = bias_g[col1];
    const float INV = 1.f / 1024.f;
    const int rbase = mtile * 16 + kg * 4;
#pragma unroll
    for (int r = 0; r < 4; ++r) {
        logits[(rbase + r) * (EE + 1) + col0] = acc0[r] * INV + b0;
        logits[(rbase + r) * (EE + 1) + col1] = acc1[r] * INV + b1;
    }
    __syncthreads();

    if (tid < TM) {
        const float* lrow = &logits[tid * (EE + 1)];
        float v1 = -INFINITY, v2 = -INFINITY;
        int   i1 = 0, i2 = 0;
        for (int e = 0; e < EE; ++e) {
            const float v = lrow[e];
            if (v > v1) { v2 = v1; i2 = i1; v1 = v; i1 = e; }
            else if (v > v2) { v2 = v; i2 = e; }
        }
        const float ed = expf(v2 - v1);
        const float inv = 1.f / (1.f + ed);
        const int tok = tBase + tid;
        out[tok * 2 + 0] = inv;
        out[tok * 2 + 1] = ed * inv;
        float* oidx = out + (size_t)2 * n_tokens;
        oidx[tok * 2 + 0] = (float)i1;
        oidx[tok * 2 + 1] = (float)i2;
    }
}

extern "C" void kernel_launch(void* const* d_in, const int* in_sizes, int n_in,
                              void* d_out, int out_size, void* d_ws, size_t ws_size,
                              hipStream_t stream) {
    const float* x = (const float*)d_in[0];
    const float* W = (const float*)d_in[1];
    const float* b = (const float*)d_in[2];
    float* out = (float*)d_out;

    const int n_tokens = in_sizes[0] / DD;      // 16384
    const int n_blocks = n_tokens / TM;         // 512

    router_kernel<<<n_blocks, THREADS, 0, stream>>>(x, W, b, out, n_tokens);
}

// Round 5
// 202.276 us; speedup vs baseline: 1.2170x; 1.0045x over previous
//
#include <hip/hip_runtime.h>
#include <math.h>

#define DD 2048
#define EE 64
#define TM 32                 // tokens per block; grid = 512 -> 2 blocks/CU
#define BK 64                 // K per chunk (2 MFMA K-steps)
#define NCHUNK (DD / BK)      // 32
#define THREADS 512           // 8 waves/block -> 16 waves/CU (50% occ target)

// LDS row layout: per 8-k group g: [hi(8 f16) 16B][lo(8 f16) 16B] at byte 32*g.
// ROWB = 8 groups * 32B + 16B pad = 272 -> bank step 4r+8g: b128 reads/writes
// spread 8-per-bank = the 128B/cyc minimum (conflict-free).
#define ROWB 272
#define XPLANE (TM * ROWB)        // 8704 B
#define WPLANE (EE * ROWB)        // 17408 B
#define BUFB   (XPLANE + WPLANE)  // 26112 B per buffer

typedef _Float16 f16x8 __attribute__((ext_vector_type(8)));
typedef float    f32x4 __attribute__((ext_vector_type(4)));

// split 8 consecutive f32 (scaled by 32) into f16 hi + f16 lo planes
__device__ static inline void split8(const float4 a, const float4 b,
                                     f16x8& hi, f16x8& lo) {
    const float S = 32.f;     // keeps lo parts out of f16 subnormal flush range
    const float v[8] = {a.x * S, a.y * S, a.z * S, a.w * S,
                        b.x * S, b.y * S, b.z * S, b.w * S};
#pragma unroll
    for (int i = 0; i < 8; ++i) {
        const _Float16 h = (_Float16)v[i];
        hi[i] = h;
        lo[i] = (_Float16)(v[i] - (float)h);
    }
}

__global__ __launch_bounds__(THREADS, 4) void router_kernel(
    const float* __restrict__ x, const float* __restrict__ W,
    const float* __restrict__ bias_g, float* __restrict__ out, int n_tokens)
{
    __shared__ __attribute__((aligned(16))) char  lds[2 * BUFB];        // 52224 B
    __shared__ __attribute__((aligned(16))) float logits[TM * (EE + 1)]; // 8320 B

    const int tid   = threadIdx.x;
    const int tBase = blockIdx.x * TM;

    // ---- staging mapping: thread owns 8 consecutive k of one row ----
    const int sr = tid >> 3;          // row 0..63
    const int sg = tid & 7;           // k-group 0..7 (k = 8*sg .. 8*sg+7)
    const bool do_x = (sr < TM);      // waves 0..3 stage x too (wave-uniform)

    const float* xrow = x + (size_t)(tBase + (sr & (TM - 1))) * DD + sg * 8;
    const float* wrow = W + (size_t)sr * DD + sg * 8;

    float4 rx0 = {0,0,0,0}, rx1 = {0,0,0,0}, rw0, rw1;

#define LOADX(c) { if (do_x) { \
        rx0 = *(const float4*)&xrow[(c) * BK];     \
        rx1 = *(const float4*)&xrow[(c) * BK + 4]; } }
#define LOADW(c) { \
        rw0 = *(const float4*)&wrow[(c) * BK];     \
        rw1 = *(const float4*)&wrow[(c) * BK + 4]; }

    // all LDS staging stores are single b128 (conflict-free 8/bank spread)
#define WRITE_STAGE(buf) { \
    char* base = lds + (size_t)(buf) * BUFB; \
    { f16x8 hi, lo; split8(rw0, rw1, hi, lo); \
      const int off = XPLANE + sr * ROWB + sg * 32; \
      *(f16x8*)(base + off)      = hi; \
      *(f16x8*)(base + off + 16) = lo; } \
    if (do_x) { f16x8 hi, lo; split8(rx0, rx1, hi, lo); \
      const int off = sr * ROWB + sg * 32; \
      *(f16x8*)(base + off)      = hi; \
      *(f16x8*)(base + off + 16) = lo; } }

    // ---- MFMA mapping (16x16x32 f16): wave = 16 tokens x 16 experts ----
    // A: lane holds A[row=l&15][k=(l>>4)*8+j]; C/D: col=l&15, row=(l>>4)*4+reg
    const int wv   = tid >> 6;        // wave 0..7
    const int lane = tid & 63;
    const int mt   = wv & 1;          // token tile
    const int nt   = wv >> 1;         // expert tile 0..3
    const int r16  = lane & 15;
    const int kg   = lane >> 4;

    const int aoff = (mt * 16 + r16) * ROWB + kg * 32;
    const int boff = XPLANE + (nt * 16 + r16) * ROWB + kg * 32;

    f32x4 acc = {0.f, 0.f, 0.f, 0.f};

    // 3-product split (skip lo*lo: ~2^-22 rel, negligible)
#define COMPUTE(buf) { \
    const char* base = lds + (size_t)(buf) * BUFB; \
    _Pragma("unroll") for (int ks = 0; ks < 2; ++ks) { \
        const f16x8 ah = *(const f16x8*)(base + aoff + ks * 128); \
        const f16x8 al = *(const f16x8*)(base + aoff + ks * 128 + 16); \
        const f16x8 bh = *(const f16x8*)(base + boff + ks * 128); \
        const f16x8 bl = *(const f16x8*)(base + boff + ks * 128 + 16); \
        acc = __builtin_amdgcn_mfma_f32_16x16x32_f16(ah, bh, acc, 0, 0, 0); \
        acc = __builtin_amdgcn_mfma_f32_16x16x32_f16(al, bh, acc, 0, 0, 0); \
        acc = __builtin_amdgcn_mfma_f32_16x16x32_f16(ah, bl, acc, 0, 0, 0); \
    } }

    // ---- pipeline: 1 barrier/chunk, regs hold chunk c+1 during compute c ----
    LOADX(0); LOADW(0);
    WRITE_STAGE(0);
    LOADX(1); LOADW(1);

    int cur = 0;
    for (int c = 0; c < NCHUNK; ++c) {
        __syncthreads();              // buf[cur] visible; buf[cur^1] free
        COMPUTE(cur);
        if (c + 1 < NCHUNK) {
            WRITE_STAGE(cur ^ 1);     // stage chunk c+1
            if (c + 2 < NCHUNK) { LOADX(c + 2); LOADW(c + 2); }
        }
        cur ^= 1;
    }

    // ---- epilogue: unscale (acc = 1024 * logit), add bias, top-2 ----
    __syncthreads();
    const int col  = nt * 16 + r16;
    const float bcol = bias_g[col];
    const float INV  = 1.f / 1024.f;
    const int rbase  = mt * 16 + kg * 4;
#pragma unroll
    for (int r = 0; r < 4; ++r)
        logits[(rbase + r) * (EE + 1) + col] = acc[r] * INV + bcol;
    __syncthreads();

    if (tid < TM) {
        const float* lrow = &logits[tid * (EE + 1)];
        float v1 = -INFINITY, v2 = -INFINITY;
        int   i1 = 0, i2 = 0;
        for (int e = 0; e < EE; ++e) {
            const float v = lrow[e];
            if (v > v1) { v2 = v1; i2 = i1; v1 = v; i1 = e; }
            else if (v > v2) { v2 = v; i2 = e; }
        }
        const float ed  = expf(v2 - v1);
        const float inv = 1.f / (1.f + ed);
        const int tok = tBase + tid;
        out[tok * 2 + 0] = inv;
        out[tok * 2 + 1] = ed * inv;
        float* oidx = out + (size_t)2 * n_tokens;
        oidx[tok * 2 + 0] = (float)i1;
        oidx[tok * 2 + 1] = (float)i2;
    }
}

extern "C" void kernel_launch(void* const* d_in, const int* in_sizes, int n_in,
                              void* d_out, int out_size, void* d_ws, size_t ws_size,
                              hipStream_t stream) {
    const float* x = (const float*)d_in[0];
    const float* W = (const float*)d_in[1];
    const float* b = (const float*)d_in[2];
    float* out = (float*)d_out;

    const int n_tokens = in_sizes[0] / DD;      // 16384
    const int n_blocks = n_tokens / TM;         // 512

    router_kernel<<<n_blocks, THREADS, 0, stream>>>(x, W, b, out, n_tokens);
}